// Round 11
// baseline (2223.383 us; speedup 1.0000x reference)
//
#include <hip/hip_runtime.h>

// Problem constants
#define B_ 32
#define S_ 2048
#define DA 32
#define DH 128
#define DS 64
#define DS2 4096

typedef _Float16 half8 __attribute__((ext_vector_type(8)));
typedef float f32x4 __attribute__((ext_vector_type(4)));

template <int CTRL>
__device__ __forceinline__ float dpp_add(float x) {
  int t = __builtin_amdgcn_update_dpp(0, __float_as_int(x), CTRL, 0xF, 0xF, true);
  return x + __int_as_float(t);
}
__device__ __forceinline__ float row_sum16(float x) {
  x = dpp_add<0xB1>(x);
  x = dpp_add<0x4E>(x);
  x = dpp_add<0x141>(x);
  x = dpp_add<0x140>(x);
  return x;
}

// async global->LDS DMA, 16 B per lane (dest = wave-uniform base + lane*16)
__device__ __forceinline__ void gl2lds16(const void* g, void* l) {
  __builtin_amdgcn_global_load_lds(
      (const __attribute__((address_space(1))) void*)g,
      (__attribute__((address_space(3))) void*)l, 16, 0, 0);
}

// ---------------------------------------------------------------------------
// R10 result: MFMA GEMM ~15us; dispatch (94.7us) = serial RNN consumer,
// latency-bound at ~1776 cy/step (2-deep register prefetch covers ~300cy of
// ~900-1500cy L3 latency). Fix: self-producing gl2lds ring -- the consumer
// wave issues slot s+3's 16 DMAs each step and gates on counted vmcnt(48)
// (never 0 in steady state), giving 3 full steps (~1000+cy) of latency
// cover with zero VGPR cost and no producer/flag protocol.
// ---------------------------------------------------------------------------
struct SharedRnn {
  float4 ring[4][16][64];   // 64 KB, 4 slots x 16 KB
};
struct SharedGemm {
  _Float16 Ah[128 * 128];   // 32 KB  [m*128 + (k ^ ((m&7)<<3))]
  _Float16 Al[128 * 128];
  _Float16 Bh[128 * 128];   // 32 KB  [nloc*128 + (k ^ ((n&7)<<3))]
  _Float16 Bl[128 * 128];
};
struct SharedMlp {
  float a_t[DA][64];        // 8 KB
  float w0_l[DA][DH];       // 16 KB
  float h0t[DH][64];        // 32 KB
};
union SharedU {
  SharedRnn r;
  SharedGemm g;
  SharedMlp m;
};

// ---------------------------------------------------------------------------
// w2 split precompute (once): w2 [k][n] fp32 -> w2h/w2l [n][k^swz] fp16,
// lo scaled by 2^11 so it stays in fp16 normal range.
// ---------------------------------------------------------------------------
__global__ __launch_bounds__(256) void k_split(
    const float* __restrict__ w2, _Float16* __restrict__ w2h,
    _Float16* __restrict__ w2l)
{
  for (int e = blockIdx.x * 256 + threadIdx.x; e < DH * DS2;
       e += gridDim.x * 256) {
    int n = e >> 7, k = e & 127;
    float v = w2[(size_t)k * DS2 + n];
    _Float16 hi = (_Float16)v;
    _Float16 lo = (_Float16)((v - (float)hi) * 2048.0f);
    int kk = k ^ ((n & 7) << 3);
    w2h[(size_t)n * DH + kk] = hi;
    w2l[(size_t)n * DH + kk] = lo;
  }
}

// ---------------------------------------------------------------------------
// MLP tile (R0-validated 256-thread compute): 64 tokens; epilogue emits the
// fp16 hi/lo split of h1 in [m][k^swz] layout (k = feature).
// ---------------------------------------------------------------------------
__device__ __forceinline__ void mlp_tile(
    const float* __restrict__ actions, const float* __restrict__ w0,
    const float* __restrict__ b0, const float* __restrict__ w1,
    const float* __restrict__ b1, _Float16* __restrict__ h1h,
    _Float16* __restrict__ h1l, int s_base, int m0, SharedMlp& sm, int tid)
{
#pragma unroll
  for (int q = 0; q < 2; ++q) {
    int g = tid + 256 * q;
    int tok = g >> 3, kq = g & 7;
    int tl = m0 + tok;
    int b = tl & 31, s = s_base + (tl >> 5);
    float4 v = *(const float4*)(actions + ((size_t)b * S_ + s) * DA + 4 * kq);
    sm.a_t[4 * kq + 0][tok] = v.x; sm.a_t[4 * kq + 1][tok] = v.y;
    sm.a_t[4 * kq + 2][tok] = v.z; sm.a_t[4 * kq + 3][tok] = v.w;
  }
#pragma unroll
  for (int q = 0; q < 4; ++q) {
    int g = tid + 256 * q;
    ((float4*)&sm.w0_l[0][0])[g] = ((const float4*)w0)[g];
  }
  __syncthreads();

  const int tm = tid & 15;
  const int tn = tid >> 4;

  float acc[4][8];
#pragma unroll
  for (int mi = 0; mi < 4; ++mi)
#pragma unroll
    for (int ni = 0; ni < 8; ++ni) acc[mi][ni] = 0.f;

#pragma unroll 4
  for (int k = 0; k < DA; ++k) {
    float4 a4 = *(const float4*)&sm.a_t[k][4 * tm];
    float4 wa = *(const float4*)&sm.w0_l[k][8 * tn];
    float4 wb = *(const float4*)&sm.w0_l[k][8 * tn + 4];
    float av[4] = {a4.x, a4.y, a4.z, a4.w};
    float wv[8] = {wa.x, wa.y, wa.z, wa.w, wb.x, wb.y, wb.z, wb.w};
#pragma unroll
    for (int mi = 0; mi < 4; ++mi)
#pragma unroll
      for (int ni = 0; ni < 8; ++ni) acc[mi][ni] += av[mi] * wv[ni];
  }
  {
    float4 ba = *(const float4*)(b0 + 8 * tn);
    float4 bb = *(const float4*)(b0 + 8 * tn + 4);
    float bv[8] = {ba.x, ba.y, ba.z, ba.w, bb.x, bb.y, bb.z, bb.w};
#pragma unroll
    for (int mi = 0; mi < 4; ++mi)
#pragma unroll
      for (int ni = 0; ni < 8; ++ni)
        sm.h0t[8 * tn + ni][4 * tm + mi] = fmaxf(acc[mi][ni] + bv[ni], 0.f);
  }
  __syncthreads();

  float acc1[4][8];
#pragma unroll
  for (int mi = 0; mi < 4; ++mi)
#pragma unroll
    for (int ni = 0; ni < 8; ++ni) acc1[mi][ni] = 0.f;

#pragma unroll 4
  for (int k = 0; k < DH; ++k) {
    float4 h4 = *(const float4*)&sm.h0t[k][4 * tm];
    float4 wa = *(const float4*)(w1 + (size_t)k * DH + 8 * tn);
    float4 wb = *(const float4*)(w1 + (size_t)k * DH + 8 * tn + 4);
    float av[4] = {h4.x, h4.y, h4.z, h4.w};
    float wv[8] = {wa.x, wa.y, wa.z, wa.w, wb.x, wb.y, wb.z, wb.w};
#pragma unroll
    for (int mi = 0; mi < 4; ++mi)
#pragma unroll
      for (int ni = 0; ni < 8; ++ni) acc1[mi][ni] += av[mi] * wv[ni];
  }
  {
    float4 ba = *(const float4*)(b1 + 8 * tn);
    float4 bb = *(const float4*)(b1 + 8 * tn + 4);
    float bv[8] = {ba.x, ba.y, ba.z, ba.w, bb.x, bb.y, bb.z, bb.w};
#pragma unroll
    for (int mi = 0; mi < 4; ++mi) {
      const int m = m0 + 4 * tm + mi;
      half8 hv, lv;
#pragma unroll
      for (int ni = 0; ni < 8; ++ni) {
        float h = fmaxf(acc1[mi][ni] + bv[ni], 0.f);
        _Float16 hi = (_Float16)h;
        hv[ni] = hi;
        lv[ni] = (_Float16)((h - (float)hi) * 2048.0f);
      }
      const int off = m * DH + ((8 * tn) ^ ((m & 7) << 3));
      *(half8*)(h1h + off) = hv;
      *(half8*)(h1l + off) = lv;
    }
  }
}

// ---------------------------------------------------------------------------
// MFMA trans GEMM (R10-validated): block owns n-strip (strip = x/7); Bh/Bl
// pinned once; per m-tile: stage Ah/Al (64 KB, linear DMA) -> MFMA -> store.
// fp16 2-way split, all four product terms kept (hh, cross*2^-11, ll*2^-22).
// C/D: col = lane&15, row = (lane>>4)*4 + reg (guide m89/m91 verified).
// ---------------------------------------------------------------------------
__device__ __forceinline__ void trans_loop(
    const _Float16* __restrict__ h1h, const _Float16* __restrict__ h1l,
    const _Float16* __restrict__ w2h, const _Float16* __restrict__ w2l,
    const float* __restrict__ b2, float* __restrict__ trans,
    int MT, int x, SharedGemm& sg, int tid)
{
  const int w  = tid >> 6;
  const int lw = tid & 63;
  const int strip = x / 7;            // 0..31
  const int idx   = x % 7;
  const int n0 = strip * 128;

  // per-wave linear 8 KB staging helper (32 KB array / 4 waves)
  auto stage32k = [&](const _Float16* src, _Float16* dst) {
    const _Float16* s = src + w * 4096 + lw * 8;
    _Float16* d = dst + w * 4096;
#pragma unroll
    for (int i = 0; i < 8; ++i)
      gl2lds16(s + i * 512, d + i * 512);
  };

  // pin B strip (w2 splits are [n][k^swz], contiguous per strip)
  stage32k(w2h + (size_t)n0 * DH, sg.Bh);
  stage32k(w2l + (size_t)n0 * DH, sg.Bl);

  const int fr = lw & 15;             // frag row/col index
  const int kg = lw >> 4;             // 0..3 k-group
  const int wr = w >> 1, wc = w & 1;  // wave quadrant

  float b2v[4];
#pragma unroll
  for (int fn = 0; fn < 4; ++fn)
    b2v[fn] = b2[n0 + wc * 64 + fn * 16 + fr];

  const f32x4 fz = {0.f, 0.f, 0.f, 0.f};

  for (int mt = idx; mt < MT; mt += 7) {
    const int m0 = mt * 128;
    stage32k(h1h + (size_t)m0 * DH, sg.Ah);
    stage32k(h1l + (size_t)m0 * DH, sg.Al);
    asm volatile("s_waitcnt vmcnt(0)" ::: "memory");
    __syncthreads();

    f32x4 ahh[4][4], axx[4][4], all_[4][4];
#pragma unroll
    for (int fm = 0; fm < 4; ++fm)
#pragma unroll
      for (int fn = 0; fn < 4; ++fn) {
        ahh[fm][fn] = fz;
        axx[fm][fn] = fz;
        all_[fm][fn] = fz;
      }

#pragma unroll
    for (int kc = 0; kc < 4; ++kc) {
      const int k0 = kc * 32 + kg * 8;
      half8 bh[4], bl[4];
#pragma unroll
      for (int fn = 0; fn < 4; ++fn) {
        const int n = wc * 64 + fn * 16 + fr;
        const int off = n * DH + (k0 ^ ((n & 7) << 3));
        bh[fn] = *(const half8*)&sg.Bh[off];
        bl[fn] = *(const half8*)&sg.Bl[off];
      }
#pragma unroll
      for (int fm = 0; fm < 4; ++fm) {
        const int m = wr * 64 + fm * 16 + fr;
        const int off = m * DH + (k0 ^ ((m & 7) << 3));
        half8 ah = *(const half8*)&sg.Ah[off];
        half8 al = *(const half8*)&sg.Al[off];
#pragma unroll
        for (int fn = 0; fn < 4; ++fn) {
          ahh[fm][fn] = __builtin_amdgcn_mfma_f32_16x16x32_f16(
              ah, bh[fn], ahh[fm][fn], 0, 0, 0);
          axx[fm][fn] = __builtin_amdgcn_mfma_f32_16x16x32_f16(
              ah, bl[fn], axx[fm][fn], 0, 0, 0);
          axx[fm][fn] = __builtin_amdgcn_mfma_f32_16x16x32_f16(
              al, bh[fn], axx[fm][fn], 0, 0, 0);
          all_[fm][fn] = __builtin_amdgcn_mfma_f32_16x16x32_f16(
              al, bl[fn], all_[fm][fn], 0, 0, 0);
        }
      }
    }
    __syncthreads();   // all LDS reads done before next tile's staging

    // epilogue: C/D layout col = lane&15, row = (lane>>4)*4 + reg
#pragma unroll
    for (int fm = 0; fm < 4; ++fm) {
#pragma unroll
      for (int fn = 0; fn < 4; ++fn) {
        const int col = n0 + wc * 64 + fn * 16 + fr;
        float* dst = trans +
            (size_t)(m0 + wr * 64 + fm * 16 + kg * 4) * DS2 + col;
#pragma unroll
        for (int r = 0; r < 4; ++r) {
          float v = ahh[fm][fn][r] + axx[fm][fn][r] * (1.0f / 2048.0f) +
                    all_[fm][fn][r] * (1.0f / 4194304.0f) + b2v[fn];
          dst[(size_t)r * DS2] = v;
        }
      }
    }
  }
}

// ---------------------------------------------------------------------------
// Standalone MLP kernel (chunk 0 priming)
// ---------------------------------------------------------------------------
__global__ __launch_bounds__(256) void k_mlp01(
    const float* __restrict__ actions, const float* __restrict__ w0,
    const float* __restrict__ b0, const float* __restrict__ w1,
    const float* __restrict__ b1, _Float16* __restrict__ h1h,
    _Float16* __restrict__ h1l, int s_base)
{
  __shared__ SharedMlp sm;
  mlp_tile(actions, w0, b0, w1, b1, h1h, h1l, s_base, blockIdx.x * 64, sm,
           threadIdx.x);
}

// ---------------------------------------------------------------------------
// Combined pipelined kernel, launch index c = 0..nch, grid 256 x 256 thr:
//  blocks 0..31  : rnn for chunk c-1 (if c>0) -- single consumer wave with
//                  self-producing gl2lds ring (4 slots, 3 in flight, counted
//                  vmcnt(48) -- never drained to 0 in steady state).
//  blocks 32..255: MFMA trans tiles for chunk c (if c<nch), then mlp c+1.
// No spin-waits anywhere: all inter-phase dependencies are cross-launch.
// ---------------------------------------------------------------------------
__global__ __launch_bounds__(256, 1) void k_comb(
    const float* __restrict__ actions, const float* __restrict__ w0,
    const float* __restrict__ b0, const float* __restrict__ w1,
    const float* __restrict__ b1, const _Float16* __restrict__ w2h,
    const _Float16* __restrict__ w2l, const float* __restrict__ b2,
    const float* __restrict__ init_hidden,
    float* __restrict__ trans0, float* __restrict__ trans1,
    _Float16* __restrict__ h1h0, _Float16* __restrict__ h1l0,
    _Float16* __restrict__ h1h1, _Float16* __restrict__ h1l1,
    float* __restrict__ hstate, float* __restrict__ out,
    int c, int SC, int nch)
{
  __shared__ SharedU sh;
  const int tid = threadIdx.x;
  const int M = SC * 32;

  if (blockIdx.x >= 32) {
    // -------------------- GEMM blocks (224) --------------------
    const int x = blockIdx.x - 32;
    if (c < nch) {
      const _Float16* h1h = (c & 1) ? h1h1 : h1h0;
      const _Float16* h1l = (c & 1) ? h1l1 : h1l0;
      float* trans = (c & 1) ? trans1 : trans0;
      trans_loop(h1h, h1l, w2h, w2l, b2, trans, M / 128, x, sh.g, tid);
      if (c + 1 < nch) {
        __syncthreads();
        _Float16* hh = ((c + 1) & 1) ? h1h1 : h1h0;
        _Float16* hl = ((c + 1) & 1) ? h1l1 : h1l0;
        for (int j = x; j < M / 64; j += 224) {
          mlp_tile(actions, w0, b0, w1, b1, hh, hl, (c + 1) * SC, j * 64,
                   sh.m, tid);
          __syncthreads();
        }
      }
    }
    return;
  }

  // ---------------- RNN blocks (chunk c-1): gl2lds ring consumer ----------
  if (c == 0) return;
  if (tid >= 64) return;              // single consumer wave per block
  const int cc = c - 1;
  const float* trans = (cc & 1) ? trans1 : trans0;
  const int s_base = cc * SC;
  const int lane = tid;
  const int b = blockIdx.x;

  const int d = lane >> 4;
  const int cq = lane & 15;
  const bool d1 = (d & 1), d2 = (d & 2);
  const int pb = lane & 48;

  float4 hq;
  if (cc == 0) {
    hq = *(const float4*)(init_hidden + 4 * cq);
    float ss0 = row_sum16(hq.x * hq.x + hq.y * hq.y + hq.z * hq.z + hq.w * hq.w);
    float iv0 = 1.0f / fmaxf(sqrtf(ss0), 1e-12f);
    hq.x *= iv0; hq.y *= iv0; hq.z *= iv0; hq.w *= iv0;
  } else {
    hq = *(const float4*)(hstate + b * DS + 4 * cq);
  }
  float inv_prev = 1.0f;

  float* outp = out + ((size_t)b * S_ + s_base) * DS + 4 * cq;
  const float* gbase = trans + (size_t)b * DS2 + 4 * lane;
  const size_t sstride = (size_t)32 * DS2;

  // issue one step's 16 KB transition slice into ring slot s&3
  // (dest wave-uniform + lane*16, source per-lane -- R0-validated pattern)
  auto issue_slot = [&](int s) {
    const float* g = gbase + (size_t)s * sstride;
    float* l = (float*)&sh.r.ring[s & 3][0][0];
#pragma unroll
    for (int q = 0; q < 16; ++q)
      gl2lds16(g + q * 256, l + q * 256);
  };

  // prologue: 3 slots in flight (48 outstanding loads)
  issue_slot(0);
  issue_slot(1);
  issue_slot(2);

  for (int s = 0; s < SC; ++s) {
    if (s + 3 < SC) {
      issue_slot(s + 3);              // reuses buffer consumed at step s-1
      asm volatile("s_waitcnt vmcnt(48)" ::: "memory");  // slot s resident
    } else {
      asm volatile("s_waitcnt vmcnt(0)" ::: "memory");   // tail drain
    }
    __builtin_amdgcn_sched_barrier(0);

    const int slot = s & 3;
    float hsel = d2 ? (d1 ? hq.w : hq.z) : (d1 ? hq.y : hq.x);
    float ax = 0.f, ay = 0.f, az = 0.f, aw = 0.f;
#pragma unroll
    for (int q = 0; q < 16; ++q) {
      float4 t4 = sh.r.ring[slot][q][lane];
      float hb = __shfl(hsel, pb + q, 64);
      ax += hb * t4.x; ay += hb * t4.y;
      az += hb * t4.z; aw += hb * t4.w;
    }
    ax += __shfl_xor(ax, 16, 64); ax += __shfl_xor(ax, 32, 64);
    ay += __shfl_xor(ay, 16, 64); ay += __shfl_xor(ay, 32, 64);
    az += __shfl_xor(az, 16, 64); az += __shfl_xor(az, 32, 64);
    aw += __shfl_xor(aw, 16, 64); aw += __shfl_xor(aw, 32, 64);
    hq.x = fmaxf(ax * inv_prev, 0.f);
    hq.y = fmaxf(ay * inv_prev, 0.f);
    hq.z = fmaxf(az * inv_prev, 0.f);
    hq.w = fmaxf(aw * inv_prev, 0.f);
    float ss = row_sum16(hq.x * hq.x + hq.y * hq.y + hq.z * hq.z + hq.w * hq.w);
    float inv = 1.0f / fmaxf(sqrtf(ss), 1e-12f);
    if (d == 0) {
      float4 o;
      o.x = hq.x * inv; o.y = hq.y * inv; o.z = hq.z * inv; o.w = hq.w * inv;
      *(float4*)(outp + (size_t)s * DS) = o;
    }
    inv_prev = inv;
  }

  if (d == 0) {
    float4 o;   // carry NORMALIZED state across chunks
    o.x = hq.x * inv_prev; o.y = hq.y * inv_prev;
    o.z = hq.z * inv_prev; o.w = hq.w * inv_prev;
    *(float4*)(hstate + b * DS + 4 * cq) = o;
  }
}

// ---------------------------------------------------------------------------
extern "C" void kernel_launch(void* const* d_in, const int* in_sizes, int n_in,
                              void* d_out, int out_size, void* d_ws, size_t ws_size,
                              hipStream_t stream) {
  const float* actions     = (const float*)d_in[0];
  const float* w0          = (const float*)d_in[1];
  const float* b0          = (const float*)d_in[2];
  const float* w1          = (const float*)d_in[3];
  const float* b1          = (const float*)d_in[4];
  const float* w2          = (const float*)d_in[5];
  const float* b2          = (const float*)d_in[6];
  const float* init_hidden = (const float*)d_in[7];
  float* out = (float*)d_out;

  // largest chunk whose workspace fits:
  // 2x trans (f32) + 4x h1 split (f16) + 2x w2 split (f16) + hstate
  int SC = 2048;
  while (SC > 4) {
    size_t need = 2 * (size_t)SC * 32 * DS2 * 4
                + 4 * (size_t)SC * 32 * DH * 2
                + 2 * (size_t)DH * DS2 * 2
                + (size_t)B_ * DS * 4;
    if (need <= ws_size) break;
    SC >>= 1;
  }
  char* p = (char*)d_ws;
  float* trans0 = (float*)p;        p += (size_t)SC * 32 * DS2 * 4;
  float* trans1 = (float*)p;        p += (size_t)SC * 32 * DS2 * 4;
  _Float16* h1h0 = (_Float16*)p;    p += (size_t)SC * 32 * DH * 2;
  _Float16* h1l0 = (_Float16*)p;    p += (size_t)SC * 32 * DH * 2;
  _Float16* h1h1 = (_Float16*)p;    p += (size_t)SC * 32 * DH * 2;
  _Float16* h1l1 = (_Float16*)p;    p += (size_t)SC * 32 * DH * 2;
  _Float16* w2h  = (_Float16*)p;    p += (size_t)DH * DS2 * 2;
  _Float16* w2l  = (_Float16*)p;    p += (size_t)DH * DS2 * 2;
  float* hstate  = (float*)p;

  const int M = SC * 32;
  const int nch = S_ / SC;

  // prime: split w2 (once) and mlp for chunk 0 -> h1h0/h1l0
  hipLaunchKernelGGL(k_split, dim3(512), dim3(256), 0, stream, w2, w2h, w2l);
  hipLaunchKernelGGL(k_mlp01, dim3(M / 64), dim3(256), 0, stream,
                     actions, w0, b0, w1, b1, h1h0, h1l0, 0);
  // pipelined combined launches
  for (int c = 0; c <= nch; ++c) {
    hipLaunchKernelGGL(k_comb, dim3(256), dim3(256), 0, stream,
                       actions, w0, b0, w1, b1, w2h, w2l, b2, init_hidden,
                       trans0, trans1, h1h0, h1l0, h1h1, h1l1, hstate, out,
                       c, SC, nch);
  }
}

// Round 12
// 1584.171 us; speedup vs baseline: 1.4035x; 1.4035x over previous
//
#include <hip/hip_runtime.h>

// Problem constants
#define B_ 32
#define S_ 2048
#define DA 32
#define DH 128
#define DS 64
#define DS2 4096

typedef _Float16 half8 __attribute__((ext_vector_type(8)));
typedef float f32x4 __attribute__((ext_vector_type(4)));

template <int CTRL>
__device__ __forceinline__ float dpp_add(float x) {
  int t = __builtin_amdgcn_update_dpp(0, __float_as_int(x), CTRL, 0xF, 0xF, true);
  return x + __int_as_float(t);
}
__device__ __forceinline__ float row_sum16(float x) {
  x = dpp_add<0xB1>(x);
  x = dpp_add<0x4E>(x);
  x = dpp_add<0x141>(x);
  x = dpp_add<0x140>(x);
  return x;
}

// async global->LDS DMA, 16 B per lane (dest = wave-uniform base + lane*16)
__device__ __forceinline__ void gl2lds16(const void* g, void* l) {
  __builtin_amdgcn_global_load_lds(
      (const __attribute__((address_space(1))) void*)g,
      (__attribute__((address_space(3))) void*)l, 16, 0, 0);
}

// ---------------------------------------------------------------------------
// R10/R11 analysis: the RNN is per-CU load-bandwidth bound -- 16 KB/step
// through ONE wave = ~1640 cy/step = 87us/chunk (matches R10's 94.7us).
// R11's single-wave ring couldn't beat the 64-outstanding per-wave cap.
// Fix: restore the R0-VALIDATED producer/consumer ring: 3 producer waves
// (stride 3, 6-slot ring, flag/cons protocol) triple the issue parallelism;
// consumer computes from LDS. GEMM stays the R10-validated MFMA fp16-split.
// ---------------------------------------------------------------------------
struct SharedRnn {
  float4 ring[6][16][64];   // 96 KB
  int flags[6];
  int cons;
};
struct SharedGemm {
  _Float16 Ah[128 * 128];   // 32 KB  [m*128 + (k ^ ((m&7)<<3))]
  _Float16 Al[128 * 128];
  _Float16 Bh[128 * 128];   // 32 KB  [nloc*128 + (k ^ ((n&7)<<3))]
  _Float16 Bl[128 * 128];
};
struct SharedMlp {
  float a_t[DA][64];        // 8 KB
  float w0_l[DA][DH];       // 16 KB
  float h0t[DH][64];        // 32 KB
};
union SharedU {
  SharedRnn r;
  SharedGemm g;
  SharedMlp m;
};

// ---------------------------------------------------------------------------
// w2 split precompute (once): w2 [k][n] fp32 -> w2h/w2l [n][k^swz] fp16,
// lo scaled by 2^11 so it stays in fp16 normal range.
// ---------------------------------------------------------------------------
__global__ __launch_bounds__(256) void k_split(
    const float* __restrict__ w2, _Float16* __restrict__ w2h,
    _Float16* __restrict__ w2l)
{
  for (int e = blockIdx.x * 256 + threadIdx.x; e < DH * DS2;
       e += gridDim.x * 256) {
    int n = e >> 7, k = e & 127;
    float v = w2[(size_t)k * DS2 + n];
    _Float16 hi = (_Float16)v;
    _Float16 lo = (_Float16)((v - (float)hi) * 2048.0f);
    int kk = k ^ ((n & 7) << 3);
    w2h[(size_t)n * DH + kk] = hi;
    w2l[(size_t)n * DH + kk] = lo;
  }
}

// ---------------------------------------------------------------------------
// MLP tile (R0-validated 256-thread compute): 64 tokens; epilogue emits the
// fp16 hi/lo split of h1 in [m][k^swz] layout (k = feature).
// ---------------------------------------------------------------------------
__device__ __forceinline__ void mlp_tile(
    const float* __restrict__ actions, const float* __restrict__ w0,
    const float* __restrict__ b0, const float* __restrict__ w1,
    const float* __restrict__ b1, _Float16* __restrict__ h1h,
    _Float16* __restrict__ h1l, int s_base, int m0, SharedMlp& sm, int tid)
{
#pragma unroll
  for (int q = 0; q < 2; ++q) {
    int g = tid + 256 * q;
    int tok = g >> 3, kq = g & 7;
    int tl = m0 + tok;
    int b = tl & 31, s = s_base + (tl >> 5);
    float4 v = *(const float4*)(actions + ((size_t)b * S_ + s) * DA + 4 * kq);
    sm.a_t[4 * kq + 0][tok] = v.x; sm.a_t[4 * kq + 1][tok] = v.y;
    sm.a_t[4 * kq + 2][tok] = v.z; sm.a_t[4 * kq + 3][tok] = v.w;
  }
#pragma unroll
  for (int q = 0; q < 4; ++q) {
    int g = tid + 256 * q;
    ((float4*)&sm.w0_l[0][0])[g] = ((const float4*)w0)[g];
  }
  __syncthreads();

  const int tm = tid & 15;
  const int tn = tid >> 4;

  float acc[4][8];
#pragma unroll
  for (int mi = 0; mi < 4; ++mi)
#pragma unroll
    for (int ni = 0; ni < 8; ++ni) acc[mi][ni] = 0.f;

#pragma unroll 4
  for (int k = 0; k < DA; ++k) {
    float4 a4 = *(const float4*)&sm.a_t[k][4 * tm];
    float4 wa = *(const float4*)&sm.w0_l[k][8 * tn];
    float4 wb = *(const float4*)&sm.w0_l[k][8 * tn + 4];
    float av[4] = {a4.x, a4.y, a4.z, a4.w};
    float wv[8] = {wa.x, wa.y, wa.z, wa.w, wb.x, wb.y, wb.z, wb.w};
#pragma unroll
    for (int mi = 0; mi < 4; ++mi)
#pragma unroll
      for (int ni = 0; ni < 8; ++ni) acc[mi][ni] += av[mi] * wv[ni];
  }
  {
    float4 ba = *(const float4*)(b0 + 8 * tn);
    float4 bb = *(const float4*)(b0 + 8 * tn + 4);
    float bv[8] = {ba.x, ba.y, ba.z, ba.w, bb.x, bb.y, bb.z, bb.w};
#pragma unroll
    for (int mi = 0; mi < 4; ++mi)
#pragma unroll
      for (int ni = 0; ni < 8; ++ni)
        sm.h0t[8 * tn + ni][4 * tm + mi] = fmaxf(acc[mi][ni] + bv[ni], 0.f);
  }
  __syncthreads();

  float acc1[4][8];
#pragma unroll
  for (int mi = 0; mi < 4; ++mi)
#pragma unroll
    for (int ni = 0; ni < 8; ++ni) acc1[mi][ni] = 0.f;

#pragma unroll 4
  for (int k = 0; k < DH; ++k) {
    float4 h4 = *(const float4*)&sm.h0t[k][4 * tm];
    float4 wa = *(const float4*)(w1 + (size_t)k * DH + 8 * tn);
    float4 wb = *(const float4*)(w1 + (size_t)k * DH + 8 * tn + 4);
    float av[4] = {h4.x, h4.y, h4.z, h4.w};
    float wv[8] = {wa.x, wa.y, wa.z, wa.w, wb.x, wb.y, wb.z, wb.w};
#pragma unroll
    for (int mi = 0; mi < 4; ++mi)
#pragma unroll
      for (int ni = 0; ni < 8; ++ni) acc1[mi][ni] += av[mi] * wv[ni];
  }
  {
    float4 ba = *(const float4*)(b1 + 8 * tn);
    float4 bb = *(const float4*)(b1 + 8 * tn + 4);
    float bv[8] = {ba.x, ba.y, ba.z, ba.w, bb.x, bb.y, bb.z, bb.w};
#pragma unroll
    for (int mi = 0; mi < 4; ++mi) {
      const int m = m0 + 4 * tm + mi;
      half8 hv, lv;
#pragma unroll
      for (int ni = 0; ni < 8; ++ni) {
        float h = fmaxf(acc1[mi][ni] + bv[ni], 0.f);
        _Float16 hi = (_Float16)h;
        hv[ni] = hi;
        lv[ni] = (_Float16)((h - (float)hi) * 2048.0f);
      }
      const int off = m * DH + ((8 * tn) ^ ((m & 7) << 3));
      *(half8*)(h1h + off) = hv;
      *(half8*)(h1l + off) = lv;
    }
  }
}

// ---------------------------------------------------------------------------
// MFMA trans GEMM (R10-validated): block owns n-strip (strip = x/7); Bh/Bl
// pinned once; per m-tile: stage Ah/Al (64 KB, linear DMA) -> MFMA -> store.
// fp16 2-way split, all four product terms kept (hh, cross*2^-11, ll*2^-22).
// C/D: col = lane&15, row = (lane>>4)*4 + reg (guide m89/m91 verified).
// ---------------------------------------------------------------------------
__device__ __forceinline__ void trans_loop(
    const _Float16* __restrict__ h1h, const _Float16* __restrict__ h1l,
    const _Float16* __restrict__ w2h, const _Float16* __restrict__ w2l,
    const float* __restrict__ b2, float* __restrict__ trans,
    int MT, int x, SharedGemm& sg, int tid)
{
  const int w  = tid >> 6;
  const int lw = tid & 63;
  const int strip = x / 7;            // 0..31
  const int idx   = x % 7;
  const int n0 = strip * 128;

  // per-wave linear 8 KB staging helper (32 KB array / 4 waves)
  auto stage32k = [&](const _Float16* src, _Float16* dst) {
    const _Float16* s = src + w * 4096 + lw * 8;
    _Float16* d = dst + w * 4096;
#pragma unroll
    for (int i = 0; i < 8; ++i)
      gl2lds16(s + i * 512, d + i * 512);
  };

  // pin B strip (w2 splits are [n][k^swz], contiguous per strip)
  stage32k(w2h + (size_t)n0 * DH, sg.Bh);
  stage32k(w2l + (size_t)n0 * DH, sg.Bl);

  const int fr = lw & 15;             // frag row/col index
  const int kg = lw >> 4;             // 0..3 k-group
  const int wr = w >> 1, wc = w & 1;  // wave quadrant

  float b2v[4];
#pragma unroll
  for (int fn = 0; fn < 4; ++fn)
    b2v[fn] = b2[n0 + wc * 64 + fn * 16 + fr];

  const f32x4 fz = {0.f, 0.f, 0.f, 0.f};

  for (int mt = idx; mt < MT; mt += 7) {
    const int m0 = mt * 128;
    stage32k(h1h + (size_t)m0 * DH, sg.Ah);
    stage32k(h1l + (size_t)m0 * DH, sg.Al);
    asm volatile("s_waitcnt vmcnt(0)" ::: "memory");
    __syncthreads();

    f32x4 ahh[4][4], axx[4][4], all_[4][4];
#pragma unroll
    for (int fm = 0; fm < 4; ++fm)
#pragma unroll
      for (int fn = 0; fn < 4; ++fn) {
        ahh[fm][fn] = fz;
        axx[fm][fn] = fz;
        all_[fm][fn] = fz;
      }

#pragma unroll
    for (int kc = 0; kc < 4; ++kc) {
      const int k0 = kc * 32 + kg * 8;
      half8 bh[4], bl[4];
#pragma unroll
      for (int fn = 0; fn < 4; ++fn) {
        const int n = wc * 64 + fn * 16 + fr;
        const int off = n * DH + (k0 ^ ((n & 7) << 3));
        bh[fn] = *(const half8*)&sg.Bh[off];
        bl[fn] = *(const half8*)&sg.Bl[off];
      }
#pragma unroll
      for (int fm = 0; fm < 4; ++fm) {
        const int m = wr * 64 + fm * 16 + fr;
        const int off = m * DH + (k0 ^ ((m & 7) << 3));
        half8 ah = *(const half8*)&sg.Ah[off];
        half8 al = *(const half8*)&sg.Al[off];
#pragma unroll
        for (int fn = 0; fn < 4; ++fn) {
          ahh[fm][fn] = __builtin_amdgcn_mfma_f32_16x16x32_f16(
              ah, bh[fn], ahh[fm][fn], 0, 0, 0);
          axx[fm][fn] = __builtin_amdgcn_mfma_f32_16x16x32_f16(
              ah, bl[fn], axx[fm][fn], 0, 0, 0);
          axx[fm][fn] = __builtin_amdgcn_mfma_f32_16x16x32_f16(
              al, bh[fn], axx[fm][fn], 0, 0, 0);
          all_[fm][fn] = __builtin_amdgcn_mfma_f32_16x16x32_f16(
              al, bl[fn], all_[fm][fn], 0, 0, 0);
        }
      }
    }
    __syncthreads();   // all LDS reads done before next tile's staging

    // epilogue: C/D layout col = lane&15, row = (lane>>4)*4 + reg
#pragma unroll
    for (int fm = 0; fm < 4; ++fm) {
#pragma unroll
      for (int fn = 0; fn < 4; ++fn) {
        const int col = n0 + wc * 64 + fn * 16 + fr;
        float* dst = trans +
            (size_t)(m0 + wr * 64 + fm * 16 + kg * 4) * DS2 + col;
#pragma unroll
        for (int r = 0; r < 4; ++r) {
          float v = ahh[fm][fn][r] + axx[fm][fn][r] * (1.0f / 2048.0f) +
                    all_[fm][fn][r] * (1.0f / 4194304.0f) + b2v[fn];
          dst[(size_t)r * DS2] = v;
        }
      }
    }
  }
}

// ---------------------------------------------------------------------------
// Standalone MLP kernel (chunk 0 priming)
// ---------------------------------------------------------------------------
__global__ __launch_bounds__(256) void k_mlp01(
    const float* __restrict__ actions, const float* __restrict__ w0,
    const float* __restrict__ b0, const float* __restrict__ w1,
    const float* __restrict__ b1, _Float16* __restrict__ h1h,
    _Float16* __restrict__ h1l, int s_base)
{
  __shared__ SharedMlp sm;
  mlp_tile(actions, w0, b0, w1, b1, h1h, h1l, s_base, blockIdx.x * 64, sm,
           threadIdx.x);
}

// ---------------------------------------------------------------------------
// Combined pipelined kernel, launch index c = 0..nch, grid 256 x 256 thr:
//  blocks 0..31  : rnn for chunk c-1 (if c>0) -- R0-VALIDATED ring protocol:
//                  consumer = wave 0, producers = waves 1..3 (stride 3,
//                  6-slot ring, flag/cons gating). 3x the load-issue
//                  parallelism of R10/R11's single-wave schemes.
//  blocks 32..255: MFMA trans tiles for chunk c (if c<nch), then mlp c+1.
// ---------------------------------------------------------------------------
__global__ __launch_bounds__(256, 1) void k_comb(
    const float* __restrict__ actions, const float* __restrict__ w0,
    const float* __restrict__ b0, const float* __restrict__ w1,
    const float* __restrict__ b1, const _Float16* __restrict__ w2h,
    const _Float16* __restrict__ w2l, const float* __restrict__ b2,
    const float* __restrict__ init_hidden,
    float* __restrict__ trans0, float* __restrict__ trans1,
    _Float16* __restrict__ h1h0, _Float16* __restrict__ h1l0,
    _Float16* __restrict__ h1h1, _Float16* __restrict__ h1l1,
    float* __restrict__ hstate, float* __restrict__ out,
    int c, int SC, int nch)
{
  __shared__ SharedU sh;
  const int tid = threadIdx.x;
  const int M = SC * 32;

  if (blockIdx.x >= 32) {
    // -------------------- GEMM blocks (224) --------------------
    const int x = blockIdx.x - 32;
    if (c < nch) {
      const _Float16* h1h = (c & 1) ? h1h1 : h1h0;
      const _Float16* h1l = (c & 1) ? h1l1 : h1l0;
      float* trans = (c & 1) ? trans1 : trans0;
      trans_loop(h1h, h1l, w2h, w2l, b2, trans, M / 128, x, sh.g, tid);
      if (c + 1 < nch) {
        __syncthreads();
        _Float16* hh = ((c + 1) & 1) ? h1h1 : h1h0;
        _Float16* hl = ((c + 1) & 1) ? h1l1 : h1l0;
        for (int j = x; j < M / 64; j += 224) {
          mlp_tile(actions, w0, b0, w1, b1, hh, hl, (c + 1) * SC, j * 64,
                   sh.m, tid);
          __syncthreads();
        }
      }
    }
    return;
  }

  // -------------------- RNN blocks (chunk c-1), R0-validated --------------
  if (c == 0) return;
  const int cc = c - 1;               // rnn chunk index
  const float* trans = (cc & 1) ? trans1 : trans0;
  const int s_base = cc * SC;
  const int wv = tid >> 6;            // 0..3
  const int lane = tid & 63;
  const int b = blockIdx.x;

  if (tid < 6) sh.r.flags[tid] = 0;
  if (tid == 6) sh.r.cons = 0;
  __syncthreads();

  const float* base = trans + (size_t)b * DS2;

  if (wv > 0) {
    // producer: steps s ≡ wv-1 (mod 3)  [R0-validated protocol]
    const int p = wv - 1;
    int prev = -1;
    for (int s = p; s < SC; s += 3) {
      while (s - __hip_atomic_load(&sh.r.cons, __ATOMIC_RELAXED,
                                   __HIP_MEMORY_SCOPE_WORKGROUP) > 5)
        __builtin_amdgcn_s_sleep(2);
      const int slot = s % 6;
      const float* g = base + (size_t)s * (32 * DS2) + 4 * lane;
      float* l = (float*)&sh.r.ring[slot][0][0];
#pragma unroll
      for (int q = 0; q < 16; ++q)
        gl2lds16(g + q * 256, l + q * 256);
      if (prev >= 0) {
        asm volatile("s_waitcnt vmcnt(16)" ::: "memory");
        __hip_atomic_store(&sh.r.flags[prev % 6], prev + 1, __ATOMIC_RELAXED,
                           __HIP_MEMORY_SCOPE_WORKGROUP);
      }
      prev = s;
    }
    if (prev >= 0) {
      asm volatile("s_waitcnt vmcnt(0)" ::: "memory");
      __hip_atomic_store(&sh.r.flags[prev % 6], prev + 1, __ATOMIC_RELAXED,
                         __HIP_MEMORY_SCOPE_WORKGROUP);
    }
  } else {
    // consumer: serial recurrence
    const int d = lane >> 4;
    const int cq = lane & 15;
    const bool d1 = (d & 1), d2 = (d & 2);
    const int pb = lane & 48;

    float4 hq;
    if (cc == 0) {
      hq = *(const float4*)(init_hidden + 4 * cq);
      float ss0 = row_sum16(hq.x * hq.x + hq.y * hq.y + hq.z * hq.z + hq.w * hq.w);
      float iv0 = 1.0f / fmaxf(sqrtf(ss0), 1e-12f);
      hq.x *= iv0; hq.y *= iv0; hq.z *= iv0; hq.w *= iv0;
    } else {
      hq = *(const float4*)(hstate + b * DS + 4 * cq);
    }
    float inv_prev = 1.0f;

    float* outp = out + ((size_t)b * S_ + s_base) * DS + 4 * cq;
    int fpre = -1;
    for (int s = 0; s < SC; ++s) {
      const int slot = s % 6;
      if (fpre < s + 1) {
        while (__hip_atomic_load(&sh.r.flags[slot], __ATOMIC_ACQUIRE,
                                 __HIP_MEMORY_SCOPE_WORKGROUP) < s + 1)
          __builtin_amdgcn_s_sleep(0);
      }
      fpre = __hip_atomic_load(&sh.r.flags[(s + 1) % 6], __ATOMIC_ACQUIRE,
                               __HIP_MEMORY_SCOPE_WORKGROUP);

      float hsel = d2 ? (d1 ? hq.w : hq.z) : (d1 ? hq.y : hq.x);
      float ax = 0.f, ay = 0.f, az = 0.f, aw = 0.f;
#pragma unroll
      for (int q = 0; q < 16; ++q) {
        float4 t4 = sh.r.ring[slot][q][lane];
        float hb = __shfl(hsel, pb + q, 64);
        ax += hb * t4.x; ay += hb * t4.y;
        az += hb * t4.z; aw += hb * t4.w;
      }
      __hip_atomic_store(&sh.r.cons, s + 1, __ATOMIC_RELAXED,
                         __HIP_MEMORY_SCOPE_WORKGROUP);

      ax += __shfl_xor(ax, 16, 64); ax += __shfl_xor(ax, 32, 64);
      ay += __shfl_xor(ay, 16, 64); ay += __shfl_xor(ay, 32, 64);
      az += __shfl_xor(az, 16, 64); az += __shfl_xor(az, 32, 64);
      aw += __shfl_xor(aw, 16, 64); aw += __shfl_xor(aw, 32, 64);
      hq.x = fmaxf(ax * inv_prev, 0.f);
      hq.y = fmaxf(ay * inv_prev, 0.f);
      hq.z = fmaxf(az * inv_prev, 0.f);
      hq.w = fmaxf(aw * inv_prev, 0.f);
      float ss = row_sum16(hq.x * hq.x + hq.y * hq.y + hq.z * hq.z + hq.w * hq.w);
      float inv = 1.0f / fmaxf(sqrtf(ss), 1e-12f);
      if (d == 0) {
        float4 o;
        o.x = hq.x * inv; o.y = hq.y * inv; o.z = hq.z * inv; o.w = hq.w * inv;
        *(float4*)(outp + (size_t)s * DS) = o;
      }
      inv_prev = inv;
    }
    if (d == 0) {
      float4 o;   // carry NORMALIZED state across chunks
      o.x = hq.x * inv_prev; o.y = hq.y * inv_prev;
      o.z = hq.z * inv_prev; o.w = hq.w * inv_prev;
      *(float4*)(hstate + b * DS + 4 * cq) = o;
    }
  }
}

// ---------------------------------------------------------------------------
extern "C" void kernel_launch(void* const* d_in, const int* in_sizes, int n_in,
                              void* d_out, int out_size, void* d_ws, size_t ws_size,
                              hipStream_t stream) {
  const float* actions     = (const float*)d_in[0];
  const float* w0          = (const float*)d_in[1];
  const float* b0          = (const float*)d_in[2];
  const float* w1          = (const float*)d_in[3];
  const float* b1          = (const float*)d_in[4];
  const float* w2          = (const float*)d_in[5];
  const float* b2          = (const float*)d_in[6];
  const float* init_hidden = (const float*)d_in[7];
  float* out = (float*)d_out;

  // largest chunk whose workspace fits:
  // 2x trans (f32) + 4x h1 split (f16) + 2x w2 split (f16) + hstate
  int SC = 2048;
  while (SC > 4) {
    size_t need = 2 * (size_t)SC * 32 * DS2 * 4
                + 4 * (size_t)SC * 32 * DH * 2
                + 2 * (size_t)DH * DS2 * 2
                + (size_t)B_ * DS * 4;
    if (need <= ws_size) break;
    SC >>= 1;
  }
  char* p = (char*)d_ws;
  float* trans0 = (float*)p;        p += (size_t)SC * 32 * DS2 * 4;
  float* trans1 = (float*)p;        p += (size_t)SC * 32 * DS2 * 4;
  _Float16* h1h0 = (_Float16*)p;    p += (size_t)SC * 32 * DH * 2;
  _Float16* h1l0 = (_Float16*)p;    p += (size_t)SC * 32 * DH * 2;
  _Float16* h1h1 = (_Float16*)p;    p += (size_t)SC * 32 * DH * 2;
  _Float16* h1l1 = (_Float16*)p;    p += (size_t)SC * 32 * DH * 2;
  _Float16* w2h  = (_Float16*)p;    p += (size_t)DH * DS2 * 2;
  _Float16* w2l  = (_Float16*)p;    p += (size_t)DH * DS2 * 2;
  float* hstate  = (float*)p;

  const int M = SC * 32;
  const int nch = S_ / SC;

  // prime: split w2 (once) and mlp for chunk 0 -> h1h0/h1l0
  hipLaunchKernelGGL(k_split, dim3(512), dim3(256), 0, stream, w2, w2h, w2l);
  hipLaunchKernelGGL(k_mlp01, dim3(M / 64), dim3(256), 0, stream,
                     actions, w0, b0, w1, b1, h1h0, h1l0, 0);
  // pipelined combined launches
  for (int c = 0; c <= nch; ++c) {
    hipLaunchKernelGGL(k_comb, dim3(256), dim3(256), 0, stream,
                       actions, w0, b0, w1, b1, w2h, w2l, b2, init_hidden,
                       trans0, trans1, h1h0, h1l0, h1h1, h1l1, hstate, out,
                       c, SC, nch);
  }
}